// Round 1
// baseline (1442.160 us; speedup 1.0000x reference)
//
#include <hip/hip_runtime.h>

#define IND 128
#define OUTD 64
#define NG 64
#define SLOPE 0.2f
#define EPSV 1e-5f

// ---------------- K1: xl = x@Wl, xr = x@Wr, xs = x@skip_W + skip_b --------
// grid: (ceil(n/64), 3), block 256. Rows staged in LDS, W chunk in registers.
__global__ __launch_bounds__(256) void gemm3_kernel(
    const float* __restrict__ x,
    const float* __restrict__ Wl, const float* __restrict__ Wr,
    const float* __restrict__ Ws, const float* __restrict__ skip_b,
    float* __restrict__ xl, float* __restrict__ xr, float* __restrict__ xs,
    int n) {
  const int which = blockIdx.y;
  const float* __restrict__ W = (which == 0) ? Wl : (which == 1) ? Wr : Ws;
  float* __restrict__ out = (which == 0) ? xl : (which == 1) ? xr : xs;

  __shared__ float sX[64][129];  // pad 129: ty-groups land on distinct banks
  int row0 = blockIdx.x * 64;
  for (int idx = threadIdx.x; idx < 64 * 128; idx += 256) {
    int r = idx >> 7, k = idx & 127;
    int row = row0 + r;
    sX[r][k] = (row < n) ? x[(size_t)row * IND + k] : 0.f;
  }
  __syncthreads();

  int tx = threadIdx.x & 15;  // cols tx*4..+3
  int ty = threadIdx.x >> 4;  // rows ty*4..+3
  float acc[4][4] = {};
  for (int kt = 0; kt < 128; kt += 16) {
    float4 wreg[16];
#pragma unroll
    for (int kk = 0; kk < 16; ++kk)
      wreg[kk] = *(const float4*)&W[(kt + kk) * OUTD + tx * 4];
#pragma unroll
    for (int kk = 0; kk < 16; ++kk) {
      float4 wv = wreg[kk];
#pragma unroll
      for (int r = 0; r < 4; ++r) {
        float xv = sX[ty * 4 + r][kt + kk];
        acc[r][0] += xv * wv.x;
        acc[r][1] += xv * wv.y;
        acc[r][2] += xv * wv.z;
        acc[r][3] += xv * wv.w;
      }
    }
  }
  float4 bias = make_float4(0.f, 0.f, 0.f, 0.f);
  if (which == 2) bias = *(const float4*)&skip_b[tx * 4];
#pragma unroll
  for (int r = 0; r < 4; ++r) {
    int row = row0 + ty * 4 + r;
    if (row < n) {
      float4 o = make_float4(acc[r][0] + bias.x, acc[r][1] + bias.y,
                             acc[r][2] + bias.z, acc[r][3] + bias.w);
      *(float4*)&out[(size_t)row * OUTD + tx * 4] = o;
    }
  }
}

// ---------------- CSR build ----------------------------------------------
__global__ void edge_hist_kernel(const int* __restrict__ dst, int* count, int E) {
  int e = blockIdx.x * blockDim.x + threadIdx.x;
  if (e < E) atomicAdd(&count[dst[e]], 1);
}

__global__ void batch_hist_kernel(const int* __restrict__ batch, int* gcnt, int n) {
  int i = blockIdx.x * blockDim.x + threadIdx.x;
  if (i < n) atomicAdd(&gcnt[batch[i]], 1);
}

// per-chunk (1024 elems) sums of count[]
__global__ __launch_bounds__(256) void chunk_sum_kernel(const int* __restrict__ count,
                                                        int* csum, int ntot) {
  int base = blockIdx.x * 1024;
  int tid = threadIdx.x;
  int s = 0;
  for (int q = 0; q < 4; ++q) {
    int i = base + tid * 4 + q;
    if (i < ntot) s += count[i];
  }
  __shared__ int lds[256];
  lds[tid] = s;
  __syncthreads();
  for (int off = 128; off > 0; off >>= 1) {
    if (tid < off) lds[tid] += lds[tid + off];
    __syncthreads();
  }
  if (tid == 0) csum[blockIdx.x] = lds[0];
}

// scan chunk sums (exclusive, in place) + scan gcnt -> goff. Tiny.
__global__ void small_scan_kernel(int* csum, int nchunks, const int* gcnt, int* goff) {
  if (threadIdx.x == 0) {
    int run = 0;
    for (int i = 0; i < nchunks; ++i) { int t = csum[i]; csum[i] = run; run += t; }
  } else if (threadIdx.x == 1) {
    int run = 0;
    for (int g = 0; g < NG; ++g) { goff[g] = run; run += gcnt[g]; }
    goff[NG] = run;
  }
}

// exclusive scan of count -> offsets (in place: offsets==count is safe; each
// element is read into registers by its owner thread before being written),
// plus a write-cursor copy woff.
__global__ __launch_bounds__(256) void scan_apply_kernel(int* count_offs,
                                                         const int* __restrict__ csum,
                                                         int* woff, int ntot) {
  __shared__ int lds[256];
  int base = blockIdx.x * 1024;
  int tid = threadIdx.x;
  int v[4];
  int s = 0;
  for (int q = 0; q < 4; ++q) {
    int i = base + tid * 4 + q;
    v[q] = (i < ntot) ? count_offs[i] : 0;
    s += v[q];
  }
  lds[tid] = s;
  __syncthreads();
  for (int off = 1; off < 256; off <<= 1) {
    int t = (tid >= off) ? lds[tid - off] : 0;
    __syncthreads();
    lds[tid] += t;
    __syncthreads();
  }
  int run = (tid ? lds[tid - 1] : 0) + csum[blockIdx.x];
  for (int q = 0; q < 4; ++q) {
    int i = base + tid * 4 + q;
    if (i < ntot) {
      count_offs[i] = run;
      if (i < ntot - 1) woff[i] = run;  // woff has n entries
      run += v[q];
    }
  }
}

__global__ void scatter_kernel(const int* __restrict__ src, const int* __restrict__ dst,
                               int* woff, int* csr, int E) {
  int e = blockIdx.x * blockDim.x + threadIdx.x;
  if (e < E) {
    int p = atomicAdd(&woff[dst[e]], 1);
    csr[p] = src[e];
  }
}

// ---------------- K5: GATv2 per-dst-node wave ----------------------------
// wave per node, lane = h*16+c. Two passes over incident edges (max, then
// exp-sum + weighted accumulate). Self loop handled inline.
__global__ __launch_bounds__(256) void edge_kernel(
    const float* __restrict__ xl, const float* __restrict__ xr,
    const int* __restrict__ offs, const int* __restrict__ csr_src,
    const float* __restrict__ att, const float* __restrict__ conv_bias,
    float* __restrict__ out_main, int n) {
  int wid = (blockIdx.x * blockDim.x + threadIdx.x) >> 6;
  int lane = threadIdx.x & 63;
  if (wid >= n) return;
  float xrc = xr[(size_t)wid * OUTD + lane];
  float attl = att[lane];
  float xself = xl[(size_t)wid * OUTD + lane];
  int e0 = offs[wid], e1 = offs[wid + 1];

  // self-loop score
  float t = xself + xrc;
  t = fmaxf(t, SLOPE * t);  // leaky_relu, slope<1
  float sself = t * attl;
  sself += __shfl_xor(sself, 1);
  sself += __shfl_xor(sself, 2);
  sself += __shfl_xor(sself, 4);
  sself += __shfl_xor(sself, 8);
  float m = sself;
  for (int e = e0; e < e1; ++e) {
    int j = csr_src[e];
    float v = xl[(size_t)j * OUTD + lane];
    float tt = v + xrc;
    tt = fmaxf(tt, SLOPE * tt);
    float sc = tt * attl;
    sc += __shfl_xor(sc, 1);
    sc += __shfl_xor(sc, 2);
    sc += __shfl_xor(sc, 4);
    sc += __shfl_xor(sc, 8);
    m = fmaxf(m, sc);
  }
  float p = __expf(sself - m);
  float denom = p;
  float acc = p * xself;
  for (int e = e0; e < e1; ++e) {
    int j = csr_src[e];
    float v = xl[(size_t)j * OUTD + lane];
    float tt = v + xrc;
    tt = fmaxf(tt, SLOPE * tt);
    float sc = tt * attl;
    sc += __shfl_xor(sc, 1);
    sc += __shfl_xor(sc, 2);
    sc += __shfl_xor(sc, 4);
    sc += __shfl_xor(sc, 8);
    p = __expf(sc - m);
    denom += p;
    acc += p * v;
  }
  out_main[(size_t)wid * OUTD + lane] = acc / denom + conv_bias[lane];
}

// ---------------- K6: per-graph norm stats -> affine A,B -----------------
__global__ __launch_bounds__(256) void stats_kernel(
    const float* __restrict__ mainv, const float* __restrict__ xs,
    const int* __restrict__ goff,
    const float* __restrict__ bn_w, const float* __restrict__ bn_b,
    const float* __restrict__ bn_ms,
    const float* __restrict__ sn_w, const float* __restrict__ sn_b,
    const float* __restrict__ sn_ms,
    float* __restrict__ Am, float* __restrict__ Bm,
    float* __restrict__ As, float* __restrict__ Bs) {
  int g = blockIdx.x;
  int start = goff[g], end = goff[g + 1];
  int col = threadIdx.x & 63, grp = threadIdx.x >> 6;
  float s1m = 0.f, s2m = 0.f, s1s = 0.f, s2s = 0.f;
  for (int node = start + grp; node < end; node += 4) {
    float vm = mainv[(size_t)node * OUTD + col];
    float vs = xs[(size_t)node * OUTD + col];
    s1m += vm; s2m += vm * vm;
    s1s += vs; s2s += vs * vs;
  }
  __shared__ float red[4][4][64];
  red[0][grp][col] = s1m; red[1][grp][col] = s2m;
  red[2][grp][col] = s1s; red[3][grp][col] = s2s;
  __syncthreads();
  if (threadIdx.x < 64) {
    int c = threadIdx.x;
    float S1m = 0.f, S2m = 0.f, S1s = 0.f, S2s = 0.f;
    for (int q = 0; q < 4; ++q) {
      S1m += red[0][q][c]; S2m += red[1][q][c];
      S1s += red[2][q][c]; S2s += red[3][q][c];
    }
    float cnt = fmaxf((float)(end - start), 1.f);
    // main norm: cen = x - mean*ms, var = E[cen^2] = E[x^2]-2a E[x]+a^2
    float meanM = S1m / cnt;
    float aM = meanM * bn_ms[c];
    float varM = S2m / cnt - 2.f * aM * meanM + aM * aM;
    float invM = rsqrtf(varM + EPSV);
    float am = bn_w[c] * invM;
    Am[g * OUTD + c] = am;
    Bm[g * OUTD + c] = bn_b[c] - am * aM;
    float meanS = S1s / cnt;
    float aS = meanS * sn_ms[c];
    float varS = S2s / cnt - 2.f * aS * meanS + aS * aS;
    float invS = rsqrtf(varS + EPSV);
    float as_ = sn_w[c] * invS;
    As[g * OUTD + c] = as_;
    Bs[g * OUTD + c] = sn_b[c] - as_ * aS;
  }
}

// ---------------- K7: apply both norms + ELU -----------------------------
__global__ __launch_bounds__(256) void final_kernel(
    const float* __restrict__ xs, const int* __restrict__ batch,
    const float* __restrict__ Am, const float* __restrict__ Bm,
    const float* __restrict__ As, const float* __restrict__ Bs,
    float* out, int n) {
  int wid = (blockIdx.x * blockDim.x + threadIdx.x) >> 6;
  int lane = threadIdx.x & 63;
  if (wid >= n) return;
  int g = batch[wid];
  float mv = out[(size_t)wid * OUTD + lane];  // pre-norm GAT output lives in d_out
  float sv = xs[(size_t)wid * OUTD + lane];
  float v = Am[g * OUTD + lane] * mv + Bm[g * OUTD + lane] +
            As[g * OUTD + lane] * sv + Bs[g * OUTD + lane];
  out[(size_t)wid * OUTD + lane] = (v > 0.f) ? v : (__expf(v) - 1.f);
}

extern "C" void kernel_launch(void* const* d_in, const int* in_sizes, int n_in,
                              void* d_out, int out_size, void* d_ws, size_t ws_size,
                              hipStream_t stream) {
  const float* x        = (const float*)d_in[0];
  const int*   ei       = (const int*)d_in[1];
  const int*   batch    = (const int*)d_in[2];
  const float* Wl       = (const float*)d_in[3];
  const float* Wr       = (const float*)d_in[4];
  const float* att      = (const float*)d_in[5];
  const float* conv_b   = (const float*)d_in[6];
  const float* skip_W   = (const float*)d_in[7];
  const float* skip_b   = (const float*)d_in[8];
  const float* bn_w     = (const float*)d_in[9];
  const float* bn_b     = (const float*)d_in[10];
  const float* bn_ms    = (const float*)d_in[11];
  const float* sn_w     = (const float*)d_in[12];
  const float* sn_b     = (const float*)d_in[13];
  const float* sn_ms    = (const float*)d_in[14];

  int n = in_sizes[0] / IND;
  int E = in_sizes[1] / 2;
  const int* src = ei;
  const int* dst = ei + E;
  float* out = (float*)d_out;

  // workspace carve-up
  char* w = (char*)d_ws;
  float* xl = (float*)w; w += (size_t)n * OUTD * 4;
  float* xr = (float*)w; w += (size_t)n * OUTD * 4;
  float* xs = (float*)w; w += (size_t)n * OUTD * 4;
  int* count = (int*)w; w += (size_t)(n + 1) * 4;   // becomes offsets in place
  int* woff  = (int*)w; w += (size_t)n * 4;
  int* csr   = (int*)w; w += (size_t)E * 4;
  int* gcnt  = (int*)w; w += (size_t)NG * 4;
  int* goff  = (int*)w; w += (size_t)(NG + 1) * 4;
  int* csum  = (int*)w; w += 256 * 4;
  float* Am  = (float*)w; w += (size_t)NG * OUTD * 4;
  float* Bm  = (float*)w; w += (size_t)NG * OUTD * 4;
  float* As  = (float*)w; w += (size_t)NG * OUTD * 4;
  float* Bs  = (float*)w; w += (size_t)NG * OUTD * 4;

  int ntot = n + 1;
  int nchunks = (ntot + 1023) / 1024;

  // zero count..gcnt (covers count, woff, csr, gcnt in one memset)
  size_t zbytes = ((size_t)(n + 1) + n + E + NG) * 4;
  hipMemsetAsync(count, 0, zbytes, stream);

  dim3 gg((n + 63) / 64, 3);
  gemm3_kernel<<<gg, 256, 0, stream>>>(x, Wl, Wr, skip_W, skip_b, xl, xr, xs, n);

  edge_hist_kernel<<<(E + 255) / 256, 256, 0, stream>>>(dst, count, E);
  batch_hist_kernel<<<(n + 255) / 256, 256, 0, stream>>>(batch, gcnt, n);
  chunk_sum_kernel<<<nchunks, 256, 0, stream>>>(count, csum, ntot);
  small_scan_kernel<<<1, 64, 0, stream>>>(csum, nchunks, gcnt, goff);
  scan_apply_kernel<<<nchunks, 256, 0, stream>>>(count, csum, woff, ntot);
  scatter_kernel<<<(E + 255) / 256, 256, 0, stream>>>(src, dst, woff, csr, E);

  edge_kernel<<<(n + 3) / 4, 256, 0, stream>>>(xl, xr, count, csr, att, conv_b, out, n);
  stats_kernel<<<NG, 256, 0, stream>>>(out, xs, goff, bn_w, bn_b, bn_ms,
                                       sn_w, sn_b, sn_ms, Am, Bm, As, Bs);
  final_kernel<<<(n + 3) / 4, 256, 0, stream>>>(xs, batch, Am, Bm, As, Bs, out, n);
}

// Round 2
// 919.452 us; speedup vs baseline: 1.5685x; 1.5685x over previous
//
#include <hip/hip_runtime.h>

#define IND 128
#define OUTD 64
#define NG 64
#define SLOPE 0.2f
#define EPSV 1e-5f

// ---------------- K1: xl = x@Wl, xr = x@Wr, xs = x@skip_W + skip_b --------
// grid: (ceil(n/64), 3), block 256. Rows staged in LDS, W chunk in registers.
__global__ __launch_bounds__(256) void gemm3_kernel(
    const float* __restrict__ x,
    const float* __restrict__ Wl, const float* __restrict__ Wr,
    const float* __restrict__ Ws, const float* __restrict__ skip_b,
    float* __restrict__ xl, float* __restrict__ xr, float* __restrict__ xs,
    int n) {
  const int which = blockIdx.y;
  const float* __restrict__ W = (which == 0) ? Wl : (which == 1) ? Wr : Ws;
  float* __restrict__ out = (which == 0) ? xl : (which == 1) ? xr : xs;

  __shared__ float sX[64][129];  // pad 129: ty-groups land on distinct banks
  int row0 = blockIdx.x * 64;
  for (int idx = threadIdx.x; idx < 64 * 128; idx += 256) {
    int r = idx >> 7, k = idx & 127;
    int row = row0 + r;
    sX[r][k] = (row < n) ? x[(size_t)row * IND + k] : 0.f;
  }
  __syncthreads();

  int tx = threadIdx.x & 15;  // cols tx*4..+3
  int ty = threadIdx.x >> 4;  // rows ty*4..+3
  float acc[4][4] = {};
  for (int kt = 0; kt < 128; kt += 16) {
    float4 wreg[16];
#pragma unroll
    for (int kk = 0; kk < 16; ++kk)
      wreg[kk] = *(const float4*)&W[(kt + kk) * OUTD + tx * 4];
#pragma unroll
    for (int kk = 0; kk < 16; ++kk) {
      float4 wv = wreg[kk];
#pragma unroll
      for (int r = 0; r < 4; ++r) {
        float xv = sX[ty * 4 + r][kt + kk];
        acc[r][0] += xv * wv.x;
        acc[r][1] += xv * wv.y;
        acc[r][2] += xv * wv.z;
        acc[r][3] += xv * wv.w;
      }
    }
  }
  float4 bias = make_float4(0.f, 0.f, 0.f, 0.f);
  if (which == 2) bias = *(const float4*)&skip_b[tx * 4];
#pragma unroll
  for (int r = 0; r < 4; ++r) {
    int row = row0 + ty * 4 + r;
    if (row < n) {
      float4 o = make_float4(acc[r][0] + bias.x, acc[r][1] + bias.y,
                             acc[r][2] + bias.z, acc[r][3] + bias.w);
      *(float4*)&out[(size_t)row * OUTD + tx * 4] = o;
    }
  }
}

// ---------------- CSR build ----------------------------------------------
__global__ void edge_hist_kernel(const int* __restrict__ dst, int* count, int E) {
  int e = blockIdx.x * blockDim.x + threadIdx.x;
  if (e < E) atomicAdd(&count[dst[e]], 1);
}

// batch[] is sorted -> graph offsets via boundary detection, zero atomics.
// goff[g] = first node index with batch >= g; goff[NG] = n.
__global__ void goff_kernel(const int* __restrict__ batch, int* goff, int n) {
  int i = blockIdx.x * blockDim.x + threadIdx.x;
  if (i >= n) return;
  int b = batch[i];
  int prev = (i == 0) ? -1 : batch[i - 1];
  for (int g = prev + 1; g <= b; ++g) goff[g] = i;
  if (i == n - 1)
    for (int g = b + 1; g <= NG; ++g) goff[g] = n;
}

// per-chunk (1024 elems) sums of count[]
__global__ __launch_bounds__(256) void chunk_sum_kernel(const int* __restrict__ count,
                                                        int* csum, int ntot) {
  int base = blockIdx.x * 1024;
  int tid = threadIdx.x;
  int s = 0;
  for (int q = 0; q < 4; ++q) {
    int i = base + tid * 4 + q;
    if (i < ntot) s += count[i];
  }
  __shared__ int lds[256];
  lds[tid] = s;
  __syncthreads();
  for (int off = 128; off > 0; off >>= 1) {
    if (tid < off) lds[tid] += lds[tid + off];
    __syncthreads();
  }
  if (tid == 0) csum[blockIdx.x] = lds[0];
}

// scan chunk sums (exclusive, in place). Tiny.
__global__ void small_scan_kernel(int* csum, int nchunks) {
  if (threadIdx.x == 0) {
    int run = 0;
    for (int i = 0; i < nchunks; ++i) { int t = csum[i]; csum[i] = run; run += t; }
  }
}

// exclusive scan of count -> offsets (in place: offsets==count is safe; each
// element is read into registers by its owner thread before being written),
// plus a write-cursor copy woff.
__global__ __launch_bounds__(256) void scan_apply_kernel(int* count_offs,
                                                         const int* __restrict__ csum,
                                                         int* woff, int ntot) {
  __shared__ int lds[256];
  int base = blockIdx.x * 1024;
  int tid = threadIdx.x;
  int v[4];
  int s = 0;
  for (int q = 0; q < 4; ++q) {
    int i = base + tid * 4 + q;
    v[q] = (i < ntot) ? count_offs[i] : 0;
    s += v[q];
  }
  lds[tid] = s;
  __syncthreads();
  for (int off = 1; off < 256; off <<= 1) {
    int t = (tid >= off) ? lds[tid - off] : 0;
    __syncthreads();
    lds[tid] += t;
    __syncthreads();
  }
  int run = (tid ? lds[tid - 1] : 0) + csum[blockIdx.x];
  for (int q = 0; q < 4; ++q) {
    int i = base + tid * 4 + q;
    if (i < ntot) {
      count_offs[i] = run;
      if (i < ntot - 1) woff[i] = run;  // woff has n entries
      run += v[q];
    }
  }
}

__global__ void scatter_kernel(const int* __restrict__ src, const int* __restrict__ dst,
                               int* woff, int* csr, int E) {
  int e = blockIdx.x * blockDim.x + threadIdx.x;
  if (e < E) {
    int p = atomicAdd(&woff[dst[e]], 1);
    csr[p] = src[e];
  }
}

// ---------------- K5: GATv2 per-dst-node wave ----------------------------
// wave per node, lane = h*16+c. Two passes over incident edges (max, then
// exp-sum + weighted accumulate). Self loop handled inline.
__global__ __launch_bounds__(256) void edge_kernel(
    const float* __restrict__ xl, const float* __restrict__ xr,
    const int* __restrict__ offs, const int* __restrict__ csr_src,
    const float* __restrict__ att, const float* __restrict__ conv_bias,
    float* __restrict__ out_main, int n) {
  int wid = (blockIdx.x * blockDim.x + threadIdx.x) >> 6;
  int lane = threadIdx.x & 63;
  if (wid >= n) return;
  float xrc = xr[(size_t)wid * OUTD + lane];
  float attl = att[lane];
  float xself = xl[(size_t)wid * OUTD + lane];
  int e0 = offs[wid], e1 = offs[wid + 1];

  // self-loop score
  float t = xself + xrc;
  t = fmaxf(t, SLOPE * t);  // leaky_relu, slope<1
  float sself = t * attl;
  sself += __shfl_xor(sself, 1);
  sself += __shfl_xor(sself, 2);
  sself += __shfl_xor(sself, 4);
  sself += __shfl_xor(sself, 8);
  float m = sself;
  for (int e = e0; e < e1; ++e) {
    int j = csr_src[e];
    float v = xl[(size_t)j * OUTD + lane];
    float tt = v + xrc;
    tt = fmaxf(tt, SLOPE * tt);
    float sc = tt * attl;
    sc += __shfl_xor(sc, 1);
    sc += __shfl_xor(sc, 2);
    sc += __shfl_xor(sc, 4);
    sc += __shfl_xor(sc, 8);
    m = fmaxf(m, sc);
  }
  float p = __expf(sself - m);
  float denom = p;
  float acc = p * xself;
  for (int e = e0; e < e1; ++e) {
    int j = csr_src[e];
    float v = xl[(size_t)j * OUTD + lane];
    float tt = v + xrc;
    tt = fmaxf(tt, SLOPE * tt);
    float sc = tt * attl;
    sc += __shfl_xor(sc, 1);
    sc += __shfl_xor(sc, 2);
    sc += __shfl_xor(sc, 4);
    sc += __shfl_xor(sc, 8);
    p = __expf(sc - m);
    denom += p;
    acc += p * v;
  }
  out_main[(size_t)wid * OUTD + lane] = acc / denom + conv_bias[lane];
}

// ---------------- K6: per-graph norm stats -> affine A,B -----------------
__global__ __launch_bounds__(256) void stats_kernel(
    const float* __restrict__ mainv, const float* __restrict__ xs,
    const int* __restrict__ goff,
    const float* __restrict__ bn_w, const float* __restrict__ bn_b,
    const float* __restrict__ bn_ms,
    const float* __restrict__ sn_w, const float* __restrict__ sn_b,
    const float* __restrict__ sn_ms,
    float* __restrict__ Am, float* __restrict__ Bm,
    float* __restrict__ As, float* __restrict__ Bs) {
  int g = blockIdx.x;
  int start = goff[g], end = goff[g + 1];
  int col = threadIdx.x & 63, grp = threadIdx.x >> 6;
  float s1m = 0.f, s2m = 0.f, s1s = 0.f, s2s = 0.f;
  for (int node = start + grp; node < end; node += 4) {
    float vm = mainv[(size_t)node * OUTD + col];
    float vs = xs[(size_t)node * OUTD + col];
    s1m += vm; s2m += vm * vm;
    s1s += vs; s2s += vs * vs;
  }
  __shared__ float red[4][4][64];
  red[0][grp][col] = s1m; red[1][grp][col] = s2m;
  red[2][grp][col] = s1s; red[3][grp][col] = s2s;
  __syncthreads();
  if (threadIdx.x < 64) {
    int c = threadIdx.x;
    float S1m = 0.f, S2m = 0.f, S1s = 0.f, S2s = 0.f;
    for (int q = 0; q < 4; ++q) {
      S1m += red[0][q][c]; S2m += red[1][q][c];
      S1s += red[2][q][c]; S2s += red[3][q][c];
    }
    float cnt = fmaxf((float)(end - start), 1.f);
    // main norm: cen = x - mean*ms, var = E[cen^2] = E[x^2]-2a E[x]+a^2
    float meanM = S1m / cnt;
    float aM = meanM * bn_ms[c];
    float varM = S2m / cnt - 2.f * aM * meanM + aM * aM;
    float invM = rsqrtf(varM + EPSV);
    float am = bn_w[c] * invM;
    Am[g * OUTD + c] = am;
    Bm[g * OUTD + c] = bn_b[c] - am * aM;
    float meanS = S1s / cnt;
    float aS = meanS * sn_ms[c];
    float varS = S2s / cnt - 2.f * aS * meanS + aS * aS;
    float invS = rsqrtf(varS + EPSV);
    float as_ = sn_w[c] * invS;
    As[g * OUTD + c] = as_;
    Bs[g * OUTD + c] = sn_b[c] - as_ * aS;
  }
}

// ---------------- K7: apply both norms + ELU -----------------------------
__global__ __launch_bounds__(256) void final_kernel(
    const float* __restrict__ xs, const int* __restrict__ batch,
    const float* __restrict__ Am, const float* __restrict__ Bm,
    const float* __restrict__ As, const float* __restrict__ Bs,
    float* out, int n) {
  int wid = (blockIdx.x * blockDim.x + threadIdx.x) >> 6;
  int lane = threadIdx.x & 63;
  if (wid >= n) return;
  int g = batch[wid];
  float mv = out[(size_t)wid * OUTD + lane];  // pre-norm GAT output lives in d_out
  float sv = xs[(size_t)wid * OUTD + lane];
  float v = Am[g * OUTD + lane] * mv + Bm[g * OUTD + lane] +
            As[g * OUTD + lane] * sv + Bs[g * OUTD + lane];
  out[(size_t)wid * OUTD + lane] = (v > 0.f) ? v : (__expf(v) - 1.f);
}

extern "C" void kernel_launch(void* const* d_in, const int* in_sizes, int n_in,
                              void* d_out, int out_size, void* d_ws, size_t ws_size,
                              hipStream_t stream) {
  const float* x        = (const float*)d_in[0];
  const int*   ei       = (const int*)d_in[1];
  const int*   batch    = (const int*)d_in[2];
  const float* Wl       = (const float*)d_in[3];
  const float* Wr       = (const float*)d_in[4];
  const float* att      = (const float*)d_in[5];
  const float* conv_b   = (const float*)d_in[6];
  const float* skip_W   = (const float*)d_in[7];
  const float* skip_b   = (const float*)d_in[8];
  const float* bn_w     = (const float*)d_in[9];
  const float* bn_b     = (const float*)d_in[10];
  const float* bn_ms    = (const float*)d_in[11];
  const float* sn_w     = (const float*)d_in[12];
  const float* sn_b     = (const float*)d_in[13];
  const float* sn_ms    = (const float*)d_in[14];

  int n = in_sizes[0] / IND;
  int E = in_sizes[1] / 2;
  const int* src = ei;
  const int* dst = ei + E;
  float* out = (float*)d_out;

  // workspace carve-up
  char* w = (char*)d_ws;
  float* xl = (float*)w; w += (size_t)n * OUTD * 4;
  float* xr = (float*)w; w += (size_t)n * OUTD * 4;
  float* xs = (float*)w; w += (size_t)n * OUTD * 4;
  int* count = (int*)w; w += (size_t)(n + 1) * 4;   // becomes offsets in place
  int* woff  = (int*)w; w += (size_t)n * 4;
  int* csr   = (int*)w; w += (size_t)E * 4;
  int* goff  = (int*)w; w += (size_t)(NG + 1) * 4;
  int* csum  = (int*)w; w += 256 * 4;
  float* Am  = (float*)w; w += (size_t)NG * OUTD * 4;
  float* Bm  = (float*)w; w += (size_t)NG * OUTD * 4;
  float* As  = (float*)w; w += (size_t)NG * OUTD * 4;
  float* Bs  = (float*)w; w += (size_t)NG * OUTD * 4;

  int ntot = n + 1;
  int nchunks = (ntot + 1023) / 1024;

  // zero only count (edge_hist atomics accumulate into it)
  hipMemsetAsync(count, 0, (size_t)(n + 1) * 4, stream);

  dim3 gg((n + 63) / 64, 3);
  gemm3_kernel<<<gg, 256, 0, stream>>>(x, Wl, Wr, skip_W, skip_b, xl, xr, xs, n);

  edge_hist_kernel<<<(E + 255) / 256, 256, 0, stream>>>(dst, count, E);
  goff_kernel<<<(n + 255) / 256, 256, 0, stream>>>(batch, goff, n);
  chunk_sum_kernel<<<nchunks, 256, 0, stream>>>(count, csum, ntot);
  small_scan_kernel<<<1, 64, 0, stream>>>(csum, nchunks);
  scan_apply_kernel<<<nchunks, 256, 0, stream>>>(count, csum, woff, ntot);
  scatter_kernel<<<(E + 255) / 256, 256, 0, stream>>>(src, dst, woff, csr, E);

  edge_kernel<<<(n + 3) / 4, 256, 0, stream>>>(xl, xr, count, csr, att, conv_b, out, n);
  stats_kernel<<<NG, 256, 0, stream>>>(out, xs, goff, bn_w, bn_b, bn_ms,
                                       sn_w, sn_b, sn_ms, Am, Bm, As, Bs);
  final_kernel<<<(n + 3) / 4, 256, 0, stream>>>(xs, batch, Am, Bm, As, Bs, out, n);
}

// Round 3
// 577.157 us; speedup vs baseline: 2.4987x; 1.5931x over previous
//
#include <hip/hip_runtime.h>

#define IND 128
#define OUTD 64
#define NG 64
#define NPART 8
#define SLOPE 0.2f
#define EPSV 1e-5f

// ---------------- K1: fused xl = x@Wl, xr = x@Wr, xs = x@skip_W + skip_b --
// grid: ceil(n/64), block 256. x tile staged in LDS ONCE, reused for all 3 W.
__global__ __launch_bounds__(256) void gemm3_kernel(
    const float* __restrict__ x,
    const float* __restrict__ Wl, const float* __restrict__ Wr,
    const float* __restrict__ Ws, const float* __restrict__ skip_b,
    float* __restrict__ xl, float* __restrict__ xr, float* __restrict__ xs,
    int n) {
  __shared__ float sX[64][129];  // pad 129: ty-groups land on distinct banks
  int row0 = blockIdx.x * 64;
  for (int idx = threadIdx.x; idx < 64 * 128; idx += 256) {
    int r = idx >> 7, k = idx & 127;
    int row = row0 + r;
    sX[r][k] = (row < n) ? x[(size_t)row * IND + k] : 0.f;
  }
  __syncthreads();

  int tx = threadIdx.x & 15;  // cols tx*4..+3
  int ty = threadIdx.x >> 4;  // rows ty*4..+3

  for (int which = 0; which < 3; ++which) {
    const float* __restrict__ W = (which == 0) ? Wl : (which == 1) ? Wr : Ws;
    float* __restrict__ out = (which == 0) ? xl : (which == 1) ? xr : xs;
    float acc[4][4] = {};
    for (int kt = 0; kt < 128; kt += 16) {
      float4 wreg[16];
#pragma unroll
      for (int kk = 0; kk < 16; ++kk)
        wreg[kk] = *(const float4*)&W[(kt + kk) * OUTD + tx * 4];
#pragma unroll
      for (int kk = 0; kk < 16; ++kk) {
        float4 wv = wreg[kk];
#pragma unroll
        for (int r = 0; r < 4; ++r) {
          float xv = sX[ty * 4 + r][kt + kk];
          acc[r][0] += xv * wv.x;
          acc[r][1] += xv * wv.y;
          acc[r][2] += xv * wv.z;
          acc[r][3] += xv * wv.w;
        }
      }
    }
    float4 bias = make_float4(0.f, 0.f, 0.f, 0.f);
    if (which == 2) bias = *(const float4*)&skip_b[tx * 4];
#pragma unroll
    for (int r = 0; r < 4; ++r) {
      int row = row0 + ty * 4 + r;
      if (row < n) {
        float4 o = make_float4(acc[r][0] + bias.x, acc[r][1] + bias.y,
                               acc[r][2] + bias.z, acc[r][3] + bias.w);
        *(float4*)&out[(size_t)row * OUTD + tx * 4] = o;
      }
    }
  }
}

// ---------------- CSR build ----------------------------------------------
__global__ void edge_hist_kernel(const int* __restrict__ dst, int* count, int E) {
  int e = blockIdx.x * blockDim.x + threadIdx.x;
  if (e < E) atomicAdd(&count[dst[e]], 1);
}

// batch[] is sorted -> graph offsets via boundary detection, zero atomics.
__global__ void goff_kernel(const int* __restrict__ batch, int* goff, int n) {
  int i = blockIdx.x * blockDim.x + threadIdx.x;
  if (i >= n) return;
  int b = batch[i];
  int prev = (i == 0) ? -1 : batch[i - 1];
  for (int g = prev + 1; g <= b; ++g) goff[g] = i;
  if (i == n - 1)
    for (int g = b + 1; g <= NG; ++g) goff[g] = n;
}

// per-chunk (1024 elems) sums of count[]
__global__ __launch_bounds__(256) void chunk_sum_kernel(const int* __restrict__ count,
                                                        int* csum, int ntot) {
  int base = blockIdx.x * 1024;
  int tid = threadIdx.x;
  int s = 0;
  for (int q = 0; q < 4; ++q) {
    int i = base + tid * 4 + q;
    if (i < ntot) s += count[i];
  }
  __shared__ int lds[256];
  lds[tid] = s;
  __syncthreads();
  for (int off = 128; off > 0; off >>= 1) {
    if (tid < off) lds[tid] += lds[tid + off];
    __syncthreads();
  }
  if (tid == 0) csum[blockIdx.x] = lds[0];
}

__global__ void small_scan_kernel(int* csum, int nchunks) {
  if (threadIdx.x == 0) {
    int run = 0;
    for (int i = 0; i < nchunks; ++i) { int t = csum[i]; csum[i] = run; run += t; }
  }
}

// exclusive scan of count -> offsets (in place), plus write-cursor copy woff.
__global__ __launch_bounds__(256) void scan_apply_kernel(int* count_offs,
                                                         const int* __restrict__ csum,
                                                         int* woff, int ntot) {
  __shared__ int lds[256];
  int base = blockIdx.x * 1024;
  int tid = threadIdx.x;
  int v[4];
  int s = 0;
  for (int q = 0; q < 4; ++q) {
    int i = base + tid * 4 + q;
    v[q] = (i < ntot) ? count_offs[i] : 0;
    s += v[q];
  }
  lds[tid] = s;
  __syncthreads();
  for (int off = 1; off < 256; off <<= 1) {
    int t = (tid >= off) ? lds[tid - off] : 0;
    __syncthreads();
    lds[tid] += t;
    __syncthreads();
  }
  int run = (tid ? lds[tid - 1] : 0) + csum[blockIdx.x];
  for (int q = 0; q < 4; ++q) {
    int i = base + tid * 4 + q;
    if (i < ntot) {
      count_offs[i] = run;
      if (i < ntot - 1) woff[i] = run;  // woff has n entries
      run += v[q];
    }
  }
}

__global__ void scatter_kernel(const int* __restrict__ src, const int* __restrict__ dst,
                               int* woff, int* csr, int E) {
  int e = blockIdx.x * blockDim.x + threadIdx.x;
  if (e < E) {
    int p = atomicAdd(&woff[dst[e]], 1);
    csr[p] = src[e];
  }
}

// ---------------- K5: GATv2 per-dst-node wave, SINGLE PASS ----------------
// wave per node, lane = h*16+c. Softmax shifted by the self-loop score
// (always present): alpha = exp(s - s_self) / sum(exp(s - s_self)) is
// mathematically identical to max-shifted softmax; score spread is O(10)
// so fp32 exp is safe. Unroll-by-2 for two independent gather+shuffle chains.
__global__ __launch_bounds__(256) void edge_kernel(
    const float* __restrict__ xl, const float* __restrict__ xr,
    const int* __restrict__ offs, const int* __restrict__ csr_src,
    const float* __restrict__ att, const float* __restrict__ conv_bias,
    float* __restrict__ out_main, int n) {
  int wid = (blockIdx.x * blockDim.x + threadIdx.x) >> 6;
  int lane = threadIdx.x & 63;
  if (wid >= n) return;
  const int base = (wid << 6) | lane;   // fits 32-bit: n*64 = 6.4M
  const float xrc = xr[base];
  const float attl = att[lane];
  const float xself = xl[base];
  int e0 = offs[wid], e1 = offs[wid + 1];

  float t = xself + xrc;
  t = fmaxf(t, SLOPE * t);
  float sself = t * attl;
  sself += __shfl_xor(sself, 1);
  sself += __shfl_xor(sself, 2);
  sself += __shfl_xor(sself, 4);
  sself += __shfl_xor(sself, 8);

  float denom = 1.f;     // exp(sself - sself)
  float acc = xself;
  int e = e0;
  for (; e + 1 < e1; e += 2) {
    int j0 = csr_src[e];
    int j1 = csr_src[e + 1];
    float v0 = xl[(j0 << 6) | lane];
    float v1 = xl[(j1 << 6) | lane];
    float t0 = v0 + xrc; t0 = fmaxf(t0, SLOPE * t0);
    float t1 = v1 + xrc; t1 = fmaxf(t1, SLOPE * t1);
    float s0 = t0 * attl;
    float s1 = t1 * attl;
    s0 += __shfl_xor(s0, 1);  s1 += __shfl_xor(s1, 1);
    s0 += __shfl_xor(s0, 2);  s1 += __shfl_xor(s1, 2);
    s0 += __shfl_xor(s0, 4);  s1 += __shfl_xor(s1, 4);
    s0 += __shfl_xor(s0, 8);  s1 += __shfl_xor(s1, 8);
    float p0 = __expf(s0 - sself);
    float p1 = __expf(s1 - sself);
    denom += p0 + p1;
    acc += p0 * v0 + p1 * v1;
  }
  if (e < e1) {
    int j = csr_src[e];
    float v = xl[(j << 6) | lane];
    float tt = v + xrc; tt = fmaxf(tt, SLOPE * tt);
    float sc = tt * attl;
    sc += __shfl_xor(sc, 1);
    sc += __shfl_xor(sc, 2);
    sc += __shfl_xor(sc, 4);
    sc += __shfl_xor(sc, 8);
    float p = __expf(sc - sself);
    denom += p;
    acc += p * v;
  }
  out_main[base] = acc / denom + conv_bias[lane];
}

// ---------------- K6a: per-graph norm partial sums (NG x NPART blocks) ----
__global__ __launch_bounds__(256) void stats_part_kernel(
    const float* __restrict__ mainv, const float* __restrict__ xs,
    const int* __restrict__ goff, float* __restrict__ part) {
  int g = blockIdx.x, q = blockIdx.y;
  int start = goff[g], end = goff[g + 1];
  int col = threadIdx.x & 63, grp = threadIdx.x >> 6;
  float s1m = 0.f, s2m = 0.f, s1s = 0.f, s2s = 0.f;
  for (int node = start + q * 4 + grp; node < end; node += 4 * NPART) {
    float vm = mainv[(node << 6) | col];
    float vs = xs[(node << 6) | col];
    s1m += vm; s2m += vm * vm;
    s1s += vs; s2s += vs * vs;
  }
  __shared__ float red[4][4][64];
  red[0][grp][col] = s1m; red[1][grp][col] = s2m;
  red[2][grp][col] = s1s; red[3][grp][col] = s2s;
  __syncthreads();
  if (threadIdx.x < 64) {
    int c = threadIdx.x;
    float* dst = &part[(g * NPART + q) * 256];
#pragma unroll
    for (int st = 0; st < 4; ++st) {
      float s = red[st][0][c] + red[st][1][c] + red[st][2][c] + red[st][3][c];
      dst[st * 64 + c] = s;
    }
  }
}

// ---------------- K6b: combine partials -> affine A,B --------------------
__global__ __launch_bounds__(256) void stats_comb_kernel(
    const float* __restrict__ part, const int* __restrict__ goff,
    const float* __restrict__ bn_w, const float* __restrict__ bn_b,
    const float* __restrict__ bn_ms,
    const float* __restrict__ sn_w, const float* __restrict__ sn_b,
    const float* __restrict__ sn_ms,
    float* __restrict__ Am, float* __restrict__ Bm,
    float* __restrict__ As, float* __restrict__ Bs) {
  int g = blockIdx.x;
  __shared__ float S[4][64];
  int tid = threadIdx.x;
  float s = 0.f;
  for (int q = 0; q < NPART; ++q) s += part[(g * NPART + q) * 256 + tid];
  S[tid >> 6][tid & 63] = s;
  __syncthreads();
  if (tid < 64) {
    int c = tid;
    float S1m = S[0][c], S2m = S[1][c], S1s = S[2][c], S2s = S[3][c];
    float cnt = fmaxf((float)(goff[g + 1] - goff[g]), 1.f);
    float meanM = S1m / cnt;
    float aM = meanM * bn_ms[c];
    float varM = S2m / cnt - 2.f * aM * meanM + aM * aM;
    float invM = rsqrtf(varM + EPSV);
    float am = bn_w[c] * invM;
    Am[g * OUTD + c] = am;
    Bm[g * OUTD + c] = bn_b[c] - am * aM;
    float meanS = S1s / cnt;
    float aS = meanS * sn_ms[c];
    float varS = S2s / cnt - 2.f * aS * meanS + aS * aS;
    float invS = rsqrtf(varS + EPSV);
    float as_ = sn_w[c] * invS;
    As[g * OUTD + c] = as_;
    Bs[g * OUTD + c] = sn_b[c] - as_ * aS;
  }
}

// ---------------- K7: apply both norms + ELU -----------------------------
__global__ __launch_bounds__(256) void final_kernel(
    const float* __restrict__ xs, const int* __restrict__ batch,
    const float* __restrict__ Am, const float* __restrict__ Bm,
    const float* __restrict__ As, const float* __restrict__ Bs,
    float* out, int n) {
  int wid = (blockIdx.x * blockDim.x + threadIdx.x) >> 6;
  int lane = threadIdx.x & 63;
  if (wid >= n) return;
  int g = batch[wid];
  float mv = out[(wid << 6) | lane];  // pre-norm GAT output lives in d_out
  float sv = xs[(wid << 6) | lane];
  float v = Am[g * OUTD + lane] * mv + Bm[g * OUTD + lane] +
            As[g * OUTD + lane] * sv + Bs[g * OUTD + lane];
  out[(wid << 6) | lane] = (v > 0.f) ? v : (__expf(v) - 1.f);
}

extern "C" void kernel_launch(void* const* d_in, const int* in_sizes, int n_in,
                              void* d_out, int out_size, void* d_ws, size_t ws_size,
                              hipStream_t stream) {
  const float* x        = (const float*)d_in[0];
  const int*   ei       = (const int*)d_in[1];
  const int*   batch    = (const int*)d_in[2];
  const float* Wl       = (const float*)d_in[3];
  const float* Wr       = (const float*)d_in[4];
  const float* att      = (const float*)d_in[5];
  const float* conv_b   = (const float*)d_in[6];
  const float* skip_W   = (const float*)d_in[7];
  const float* skip_b   = (const float*)d_in[8];
  const float* bn_w     = (const float*)d_in[9];
  const float* bn_b     = (const float*)d_in[10];
  const float* bn_ms    = (const float*)d_in[11];
  const float* sn_w     = (const float*)d_in[12];
  const float* sn_b     = (const float*)d_in[13];
  const float* sn_ms    = (const float*)d_in[14];

  int n = in_sizes[0] / IND;
  int E = in_sizes[1] / 2;
  const int* src = ei;
  const int* dst = ei + E;
  float* out = (float*)d_out;

  // workspace carve-up
  char* w = (char*)d_ws;
  float* xl = (float*)w; w += (size_t)n * OUTD * 4;
  float* xr = (float*)w; w += (size_t)n * OUTD * 4;
  float* xs = (float*)w; w += (size_t)n * OUTD * 4;
  int* count = (int*)w; w += (size_t)(n + 1) * 4;   // becomes offsets in place
  int* woff  = (int*)w; w += (size_t)n * 4;
  int* csr   = (int*)w; w += (size_t)E * 4;
  int* goff  = (int*)w; w += (size_t)(NG + 1) * 4;
  int* csum  = (int*)w; w += 256 * 4;
  float* Am  = (float*)w; w += (size_t)NG * OUTD * 4;
  float* Bm  = (float*)w; w += (size_t)NG * OUTD * 4;
  float* As  = (float*)w; w += (size_t)NG * OUTD * 4;
  float* Bs  = (float*)w; w += (size_t)NG * OUTD * 4;
  float* part = (float*)w; w += (size_t)NG * NPART * 256 * 4;

  int ntot = n + 1;
  int nchunks = (ntot + 1023) / 1024;

  hipMemsetAsync(count, 0, (size_t)(n + 1) * 4, stream);

  gemm3_kernel<<<(n + 63) / 64, 256, 0, stream>>>(x, Wl, Wr, skip_W, skip_b,
                                                  xl, xr, xs, n);

  edge_hist_kernel<<<(E + 255) / 256, 256, 0, stream>>>(dst, count, E);
  goff_kernel<<<(n + 255) / 256, 256, 0, stream>>>(batch, goff, n);
  chunk_sum_kernel<<<nchunks, 256, 0, stream>>>(count, csum, ntot);
  small_scan_kernel<<<1, 64, 0, stream>>>(csum, nchunks);
  scan_apply_kernel<<<nchunks, 256, 0, stream>>>(count, csum, woff, ntot);
  scatter_kernel<<<(E + 255) / 256, 256, 0, stream>>>(src, dst, woff, csr, E);

  edge_kernel<<<(n + 3) / 4, 256, 0, stream>>>(xl, xr, count, csr, att, conv_b, out, n);
  dim3 sg(NG, NPART);
  stats_part_kernel<<<sg, 256, 0, stream>>>(out, xs, goff, part);
  stats_comb_kernel<<<NG, 256, 0, stream>>>(part, goff, bn_w, bn_b, bn_ms,
                                            sn_w, sn_b, sn_ms, Am, Bm, As, Bs);
  final_kernel<<<(n + 3) / 4, 256, 0, stream>>>(xs, batch, Am, Bm, As, Bs, out, n);
}

// Round 4
// 528.423 us; speedup vs baseline: 2.7292x; 1.0922x over previous
//
#include <hip/hip_runtime.h>

#define IND 128
#define OUTD 64
#define NG 64
#define NPART 8
#define NSTRIPE 256
#define SLOPE 0.2f
#define EPSV 1e-5f

// ---------------- K1: fused xl = x@Wl, xr = x@Wr, xs = x@skip_W + skip_b --
// grid: ceil(n/64), block 256. x tile staged in LDS once (float4 rows,
// stride 132 floats keeps 16B alignment and distinct banks); each x fragment
// is read from LDS ONCE and reused for all three weight matrices.
__global__ __launch_bounds__(256) void gemm3_kernel(
    const float* __restrict__ x,
    const float* __restrict__ Wl, const float* __restrict__ Wr,
    const float* __restrict__ Ws, const float* __restrict__ skip_b,
    float* __restrict__ xl, float* __restrict__ xr, float* __restrict__ xs,
    int n) {
  __shared__ float sX[64 * 132];
  int row0 = blockIdx.x * 64;
  const float4* x4 = (const float4*)x;  // row stride 32 float4
  for (int i = threadIdx.x; i < 2048; i += 256) {
    int r = i >> 5, c = i & 31;
    int row = row0 + r;
    float4 v = make_float4(0.f, 0.f, 0.f, 0.f);
    if (row < n) v = x4[(size_t)row * 32 + c];
    *(float4*)&sX[r * 132 + c * 4] = v;
  }
  __syncthreads();

  int tx = threadIdx.x & 15;  // cols tx*4..+3
  int ty = threadIdx.x >> 4;  // rows ty*4..+3
  const float* Wp[3] = {Wl, Wr, Ws};
  float acc[3][4][4] = {};

  for (int kt = 0; kt < 128; kt += 4) {
    float4 xv[4];
#pragma unroll
    for (int r = 0; r < 4; ++r)
      xv[r] = *(const float4*)&sX[(ty * 4 + r) * 132 + kt];
#pragma unroll
    for (int which = 0; which < 3; ++which) {
      const float* W = Wp[which];
      float4 w0 = *(const float4*)&W[(kt + 0) * OUTD + tx * 4];
      float4 w1 = *(const float4*)&W[(kt + 1) * OUTD + tx * 4];
      float4 w2 = *(const float4*)&W[(kt + 2) * OUTD + tx * 4];
      float4 w3 = *(const float4*)&W[(kt + 3) * OUTD + tx * 4];
#pragma unroll
      for (int r = 0; r < 4; ++r) {
        float x0 = xv[r].x, x1 = xv[r].y, x2 = xv[r].z, x3 = xv[r].w;
        acc[which][r][0] += x0 * w0.x + x1 * w1.x + x2 * w2.x + x3 * w3.x;
        acc[which][r][1] += x0 * w0.y + x1 * w1.y + x2 * w2.y + x3 * w3.y;
        acc[which][r][2] += x0 * w0.z + x1 * w1.z + x2 * w2.z + x3 * w3.z;
        acc[which][r][3] += x0 * w0.w + x1 * w1.w + x2 * w2.w + x3 * w3.w;
      }
    }
  }

#pragma unroll
  for (int which = 0; which < 3; ++which) {
    float* out = (which == 0) ? xl : (which == 1) ? xr : xs;
    float4 bias = make_float4(0.f, 0.f, 0.f, 0.f);
    if (which == 2) bias = *(const float4*)&skip_b[tx * 4];
#pragma unroll
    for (int r = 0; r < 4; ++r) {
      int row = row0 + ty * 4 + r;
      if (row < n) {
        float4 o = make_float4(acc[which][r][0] + bias.x, acc[which][r][1] + bias.y,
                               acc[which][r][2] + bias.z, acc[which][r][3] + bias.w);
        *(float4*)&out[(size_t)row * OUTD + tx * 4] = o;
      }
    }
  }
}

// ---------------- CSR build (XCD-range partitioned) -----------------------
// block b: dst-range (b&7), edge-stripe (b>>3). With round-robin block->XCD
// dispatch, each range's atomics/writes stay in ONE XCD's L2 (50 KB..800 KB,
// L2-resident -> write merging instead of 16x amplification). Correct under
// any mapping; the partition only buys locality.
__global__ __launch_bounds__(256) void edge_hist_kernel(
    const int* __restrict__ dst, int* count, int E, int n8) {
  int r = blockIdx.x & 7;
  int stripe = blockIdx.x >> 3;
  int lo = r * n8, hi = lo + n8;
  int per = (E + NSTRIPE - 1) / NSTRIPE;
  int s0 = stripe * per;
  int s1 = min(E, s0 + per);
  for (int e = s0 + (int)threadIdx.x; e < s1; e += 256) {
    int d = dst[e];
    if (d >= lo && d < hi) atomicAdd(&count[d], 1);
  }
}

__global__ __launch_bounds__(256) void scatter_kernel(
    const int* __restrict__ src, const int* __restrict__ dst,
    int* woff, int* csr, int E, int n8) {
  int r = blockIdx.x & 7;
  int stripe = blockIdx.x >> 3;
  int lo = r * n8, hi = lo + n8;
  int per = (E + NSTRIPE - 1) / NSTRIPE;
  int s0 = stripe * per;
  int s1 = min(E, s0 + per);
  for (int e = s0 + (int)threadIdx.x; e < s1; e += 256) {
    int d = dst[e];
    if (d >= lo && d < hi) {
      int p = atomicAdd(&woff[d], 1);
      csr[p] = src[e];
    }
  }
}

// batch[] is sorted -> graph offsets via boundary detection, zero atomics.
__global__ void goff_kernel(const int* __restrict__ batch, int* goff, int n) {
  int i = blockIdx.x * blockDim.x + threadIdx.x;
  if (i >= n) return;
  int b = batch[i];
  int prev = (i == 0) ? -1 : batch[i - 1];
  for (int g = prev + 1; g <= b; ++g) goff[g] = i;
  if (i == n - 1)
    for (int g = b + 1; g <= NG; ++g) goff[g] = n;
}

// per-chunk (1024 elems) sums of count[]
__global__ __launch_bounds__(256) void chunk_sum_kernel(const int* __restrict__ count,
                                                        int* csum, int ntot) {
  int base = blockIdx.x * 1024;
  int tid = threadIdx.x;
  int s = 0;
  for (int q = 0; q < 4; ++q) {
    int i = base + tid * 4 + q;
    if (i < ntot) s += count[i];
  }
  __shared__ int lds[256];
  lds[tid] = s;
  __syncthreads();
  for (int off = 128; off > 0; off >>= 1) {
    if (tid < off) lds[tid] += lds[tid + off];
    __syncthreads();
  }
  if (tid == 0) csum[blockIdx.x] = lds[0];
}

__global__ void small_scan_kernel(int* csum, int nchunks) {
  if (threadIdx.x == 0) {
    int run = 0;
    for (int i = 0; i < nchunks; ++i) { int t = csum[i]; csum[i] = run; run += t; }
  }
}

// exclusive scan of count -> offsets (in place), plus write-cursor copy woff.
__global__ __launch_bounds__(256) void scan_apply_kernel(int* count_offs,
                                                         const int* __restrict__ csum,
                                                         int* woff, int ntot) {
  __shared__ int lds[256];
  int base = blockIdx.x * 1024;
  int tid = threadIdx.x;
  int v[4];
  int s = 0;
  for (int q = 0; q < 4; ++q) {
    int i = base + tid * 4 + q;
    v[q] = (i < ntot) ? count_offs[i] : 0;
    s += v[q];
  }
  lds[tid] = s;
  __syncthreads();
  for (int off = 1; off < 256; off <<= 1) {
    int t = (tid >= off) ? lds[tid - off] : 0;
    __syncthreads();
    lds[tid] += t;
    __syncthreads();
  }
  int run = (tid ? lds[tid - 1] : 0) + csum[blockIdx.x];
  for (int q = 0; q < 4; ++q) {
    int i = base + tid * 4 + q;
    if (i < ntot) {
      count_offs[i] = run;
      if (i < ntot - 1) woff[i] = run;  // woff has n entries
      run += v[q];
    }
  }
}

// ---------------- K5: GATv2 per-dst-node wave, SINGLE PASS ----------------
// Softmax shifted by the self-loop score: identical alpha, one edge pass.
__global__ __launch_bounds__(256) void edge_kernel(
    const float* __restrict__ xl, const float* __restrict__ xr,
    const int* __restrict__ offs, const int* __restrict__ csr_src,
    const float* __restrict__ att, const float* __restrict__ conv_bias,
    float* __restrict__ out_main, int n) {
  int wid = (blockIdx.x * blockDim.x + threadIdx.x) >> 6;
  int lane = threadIdx.x & 63;
  if (wid >= n) return;
  const int base = (wid << 6) | lane;
  const float xrc = xr[base];
  const float attl = att[lane];
  const float xself = xl[base];
  int e0 = offs[wid], e1 = offs[wid + 1];

  float t = xself + xrc;
  t = fmaxf(t, SLOPE * t);
  float sself = t * attl;
  sself += __shfl_xor(sself, 1);
  sself += __shfl_xor(sself, 2);
  sself += __shfl_xor(sself, 4);
  sself += __shfl_xor(sself, 8);

  float denom = 1.f;
  float acc = xself;
  int e = e0;
  for (; e + 1 < e1; e += 2) {
    int j0 = csr_src[e];
    int j1 = csr_src[e + 1];
    float v0 = xl[(j0 << 6) | lane];
    float v1 = xl[(j1 << 6) | lane];
    float t0 = v0 + xrc; t0 = fmaxf(t0, SLOPE * t0);
    float t1 = v1 + xrc; t1 = fmaxf(t1, SLOPE * t1);
    float s0 = t0 * attl;
    float s1 = t1 * attl;
    s0 += __shfl_xor(s0, 1);  s1 += __shfl_xor(s1, 1);
    s0 += __shfl_xor(s0, 2);  s1 += __shfl_xor(s1, 2);
    s0 += __shfl_xor(s0, 4);  s1 += __shfl_xor(s1, 4);
    s0 += __shfl_xor(s0, 8);  s1 += __shfl_xor(s1, 8);
    float p0 = __expf(s0 - sself);
    float p1 = __expf(s1 - sself);
    denom += p0 + p1;
    acc += p0 * v0 + p1 * v1;
  }
  if (e < e1) {
    int j = csr_src[e];
    float v = xl[(j << 6) | lane];
    float tt = v + xrc; tt = fmaxf(tt, SLOPE * tt);
    float sc = tt * attl;
    sc += __shfl_xor(sc, 1);
    sc += __shfl_xor(sc, 2);
    sc += __shfl_xor(sc, 4);
    sc += __shfl_xor(sc, 8);
    float p = __expf(sc - sself);
    denom += p;
    acc += p * v;
  }
  out_main[base] = acc / denom + conv_bias[lane];
}

// ---------------- K6a: per-graph norm partial sums (NG x NPART blocks) ----
__global__ __launch_bounds__(256) void stats_part_kernel(
    const float* __restrict__ mainv, const float* __restrict__ xs,
    const int* __restrict__ goff, float* __restrict__ part) {
  int g = blockIdx.x, q = blockIdx.y;
  int start = goff[g], end = goff[g + 1];
  int col = threadIdx.x & 63, grp = threadIdx.x >> 6;
  float s1m = 0.f, s2m = 0.f, s1s = 0.f, s2s = 0.f;
  for (int node = start + q * 4 + grp; node < end; node += 4 * NPART) {
    float vm = mainv[(node << 6) | col];
    float vs = xs[(node << 6) | col];
    s1m += vm; s2m += vm * vm;
    s1s += vs; s2s += vs * vs;
  }
  __shared__ float red[4][4][64];
  red[0][grp][col] = s1m; red[1][grp][col] = s2m;
  red[2][grp][col] = s1s; red[3][grp][col] = s2s;
  __syncthreads();
  if (threadIdx.x < 64) {
    int c = threadIdx.x;
    float* dst = &part[(g * NPART + q) * 256];
#pragma unroll
    for (int st = 0; st < 4; ++st) {
      float s = red[st][0][c] + red[st][1][c] + red[st][2][c] + red[st][3][c];
      dst[st * 64 + c] = s;
    }
  }
}

// ---------------- K6b: combine partials -> affine A,B --------------------
__global__ __launch_bounds__(256) void stats_comb_kernel(
    const float* __restrict__ part, const int* __restrict__ goff,
    const float* __restrict__ bn_w, const float* __restrict__ bn_b,
    const float* __restrict__ bn_ms,
    const float* __restrict__ sn_w, const float* __restrict__ sn_b,
    const float* __restrict__ sn_ms,
    float* __restrict__ Am, float* __restrict__ Bm,
    float* __restrict__ As, float* __restrict__ Bs) {
  int g = blockIdx.x;
  __shared__ float S[4][64];
  int tid = threadIdx.x;
  float s = 0.f;
  for (int q = 0; q < NPART; ++q) s += part[(g * NPART + q) * 256 + tid];
  S[tid >> 6][tid & 63] = s;
  __syncthreads();
  if (tid < 64) {
    int c = tid;
    float S1m = S[0][c], S2m = S[1][c], S1s = S[2][c], S2s = S[3][c];
    float cnt = fmaxf((float)(goff[g + 1] - goff[g]), 1.f);
    float meanM = S1m / cnt;
    float aM = meanM * bn_ms[c];
    float varM = S2m / cnt - 2.f * aM * meanM + aM * aM;
    float invM = rsqrtf(varM + EPSV);
    float am = bn_w[c] * invM;
    Am[g * OUTD + c] = am;
    Bm[g * OUTD + c] = bn_b[c] - am * aM;
    float meanS = S1s / cnt;
    float aS = meanS * sn_ms[c];
    float varS = S2s / cnt - 2.f * aS * meanS + aS * aS;
    float invS = rsqrtf(varS + EPSV);
    float as_ = sn_w[c] * invS;
    As[g * OUTD + c] = as_;
    Bs[g * OUTD + c] = sn_b[c] - as_ * aS;
  }
}

// ---------------- K7: apply both norms + ELU -----------------------------
__global__ __launch_bounds__(256) void final_kernel(
    const float* __restrict__ xs, const int* __restrict__ batch,
    const float* __restrict__ Am, const float* __restrict__ Bm,
    const float* __restrict__ As, const float* __restrict__ Bs,
    float* out, int n) {
  int wid = (blockIdx.x * blockDim.x + threadIdx.x) >> 6;
  int lane = threadIdx.x & 63;
  if (wid >= n) return;
  int g = batch[wid];
  float mv = out[(wid << 6) | lane];
  float sv = xs[(wid << 6) | lane];
  float v = Am[g * OUTD + lane] * mv + Bm[g * OUTD + lane] +
            As[g * OUTD + lane] * sv + Bs[g * OUTD + lane];
  out[(wid << 6) | lane] = (v > 0.f) ? v : (__expf(v) - 1.f);
}

extern "C" void kernel_launch(void* const* d_in, const int* in_sizes, int n_in,
                              void* d_out, int out_size, void* d_ws, size_t ws_size,
                              hipStream_t stream) {
  const float* x        = (const float*)d_in[0];
  const int*   ei       = (const int*)d_in[1];
  const int*   batch    = (const int*)d_in[2];
  const float* Wl       = (const float*)d_in[3];
  const float* Wr       = (const float*)d_in[4];
  const float* att      = (const float*)d_in[5];
  const float* conv_b   = (const float*)d_in[6];
  const float* skip_W   = (const float*)d_in[7];
  const float* skip_b   = (const float*)d_in[8];
  const float* bn_w     = (const float*)d_in[9];
  const float* bn_b     = (const float*)d_in[10];
  const float* bn_ms    = (const float*)d_in[11];
  const float* sn_w     = (const float*)d_in[12];
  const float* sn_b     = (const float*)d_in[13];
  const float* sn_ms    = (const float*)d_in[14];

  int n = in_sizes[0] / IND;
  int E = in_sizes[1] / 2;
  const int* src = ei;
  const int* dst = ei + E;
  float* out = (float*)d_out;

  // workspace carve-up
  char* w = (char*)d_ws;
  float* xl = (float*)w; w += (size_t)n * OUTD * 4;
  float* xr = (float*)w; w += (size_t)n * OUTD * 4;
  float* xs = (float*)w; w += (size_t)n * OUTD * 4;
  int* count = (int*)w; w += (size_t)(n + 1) * 4;   // becomes offsets in place
  int* woff  = (int*)w; w += (size_t)n * 4;
  int* csr   = (int*)w; w += (size_t)E * 4;
  int* goff  = (int*)w; w += (size_t)(NG + 1) * 4;
  int* csum  = (int*)w; w += 256 * 4;
  float* Am  = (float*)w; w += (size_t)NG * OUTD * 4;
  float* Bm  = (float*)w; w += (size_t)NG * OUTD * 4;
  float* As  = (float*)w; w += (size_t)NG * OUTD * 4;
  float* Bs  = (float*)w; w += (size_t)NG * OUTD * 4;
  float* part = (float*)w; w += (size_t)NG * NPART * 256 * 4;

  int ntot = n + 1;
  int nchunks = (ntot + 1023) / 1024;
  int n8 = (n + 7) / 8;

  hipMemsetAsync(count, 0, (size_t)(n + 1) * 4, stream);

  gemm3_kernel<<<(n + 63) / 64, 256, 0, stream>>>(x, Wl, Wr, skip_W, skip_b,
                                                  xl, xr, xs, n);

  edge_hist_kernel<<<8 * NSTRIPE, 256, 0, stream>>>(dst, count, E, n8);
  goff_kernel<<<(n + 255) / 256, 256, 0, stream>>>(batch, goff, n);
  chunk_sum_kernel<<<nchunks, 256, 0, stream>>>(count, csum, ntot);
  small_scan_kernel<<<1, 64, 0, stream>>>(csum, nchunks);
  scan_apply_kernel<<<nchunks, 256, 0, stream>>>(count, csum, woff, ntot);
  scatter_kernel<<<8 * NSTRIPE, 256, 0, stream>>>(src, dst, woff, csr, E, n8);

  edge_kernel<<<(n + 3) / 4, 256, 0, stream>>>(xl, xr, count, csr, att, conv_b, out, n);
  dim3 sg(NG, NPART);
  stats_part_kernel<<<sg, 256, 0, stream>>>(out, xs, goff, part);
  stats_comb_kernel<<<NG, 256, 0, stream>>>(part, goff, bn_w, bn_b, bn_ms,
                                            sn_w, sn_b, sn_ms, Am, Bm, As, Bs);
  final_kernel<<<(n + 3) / 4, 256, 0, stream>>>(xs, batch, Am, Bm, As, Bs, out, n);
}

// Round 5
// 451.701 us; speedup vs baseline: 3.1927x; 1.1699x over previous
//
#include <hip/hip_runtime.h>

#define IND 128
#define OUTD 64
#define NG 64
#define NPART 8
#define NSTRIPE 256
#define SLOPE 0.2f
#define EPSV 1e-5f

// ================= MEGA 1: gemm3 || edge_hist || goff =====================
// Independent stages fused by blockIdx range so the VALU-bound gemm and the
// atomic/latency-bound histogram co-run on the CUs instead of serializing.

__device__ __forceinline__ void gemm3_body(
    int bx, const float* __restrict__ x,
    const float* __restrict__ Wl, const float* __restrict__ Wr,
    const float* __restrict__ Ws, const float* __restrict__ skip_b,
    float* __restrict__ xl, float* __restrict__ xr, float* __restrict__ xs,
    int n) {
  __shared__ float sX[64 * 132];
  int row0 = bx * 64;
  const float4* x4 = (const float4*)x;  // row stride 32 float4
  for (int i = threadIdx.x; i < 2048; i += 256) {
    int r = i >> 5, c = i & 31;
    int row = row0 + r;
    float4 v = make_float4(0.f, 0.f, 0.f, 0.f);
    if (row < n) v = x4[(size_t)row * 32 + c];
    *(float4*)&sX[r * 132 + c * 4] = v;
  }
  __syncthreads();

  int tx = threadIdx.x & 15;  // cols tx*4..+3
  int ty = threadIdx.x >> 4;  // rows ty*4..+3
  const float* Wp[3] = {Wl, Wr, Ws};
  float acc[3][4][4] = {};

  for (int kt = 0; kt < 128; kt += 4) {
    float4 xv[4];
#pragma unroll
    for (int r = 0; r < 4; ++r)
      xv[r] = *(const float4*)&sX[(ty * 4 + r) * 132 + kt];
#pragma unroll
    for (int which = 0; which < 3; ++which) {
      const float* W = Wp[which];
      float4 w0 = *(const float4*)&W[(kt + 0) * OUTD + tx * 4];
      float4 w1 = *(const float4*)&W[(kt + 1) * OUTD + tx * 4];
      float4 w2 = *(const float4*)&W[(kt + 2) * OUTD + tx * 4];
      float4 w3 = *(const float4*)&W[(kt + 3) * OUTD + tx * 4];
#pragma unroll
      for (int r = 0; r < 4; ++r) {
        float x0 = xv[r].x, x1 = xv[r].y, x2 = xv[r].z, x3 = xv[r].w;
        acc[which][r][0] += x0 * w0.x + x1 * w1.x + x2 * w2.x + x3 * w3.x;
        acc[which][r][1] += x0 * w0.y + x1 * w1.y + x2 * w2.y + x3 * w3.y;
        acc[which][r][2] += x0 * w0.z + x1 * w1.z + x2 * w2.z + x3 * w3.z;
        acc[which][r][3] += x0 * w0.w + x1 * w1.w + x2 * w2.w + x3 * w3.w;
      }
    }
  }

#pragma unroll
  for (int which = 0; which < 3; ++which) {
    float* out = (which == 0) ? xl : (which == 1) ? xr : xs;
    float4 bias = make_float4(0.f, 0.f, 0.f, 0.f);
    if (which == 2) bias = *(const float4*)&skip_b[tx * 4];
#pragma unroll
    for (int r = 0; r < 4; ++r) {
      int row = row0 + ty * 4 + r;
      if (row < n) {
        float4 o = make_float4(acc[which][r][0] + bias.x, acc[which][r][1] + bias.y,
                               acc[which][r][2] + bias.z, acc[which][r][3] + bias.w);
        *(float4*)&out[(size_t)row * OUTD + tx * 4] = o;
      }
    }
  }
}

// XCD-range-partitioned histogram: block handles dst-range (b&7) over edge
// stripe (b>>3) so each range's atomics stay in one XCD's L2.
__device__ __forceinline__ void hist_body(int bx, const int* __restrict__ dst,
                                          int* count, int E, int n8) {
  int r = bx & 7;
  int stripe = bx >> 3;
  int lo = r * n8, hi = lo + n8;
  int per = (E + NSTRIPE - 1) / NSTRIPE;
  int s0 = stripe * per;
  int s1 = min(E, s0 + per);
  for (int e = s0 + (int)threadIdx.x; e < s1; e += 256) {
    int d = dst[e];
    if (d >= lo && d < hi) atomicAdd(&count[d], 1);
  }
}

// batch[] sorted -> graph offsets via boundary detection, zero atomics.
__device__ __forceinline__ void goff_body(int bx, const int* __restrict__ batch,
                                          int* goff, int n) {
  int i = bx * 256 + threadIdx.x;
  if (i >= n) return;
  int b = batch[i];
  int prev = (i == 0) ? -1 : batch[i - 1];
  for (int g = prev + 1; g <= b; ++g) goff[g] = i;
  if (i == n - 1)
    for (int g = b + 1; g <= NG; ++g) goff[g] = n;
}

__global__ __launch_bounds__(256) void mega1_kernel(
    const float* __restrict__ x,
    const float* __restrict__ Wl, const float* __restrict__ Wr,
    const float* __restrict__ Ws, const float* __restrict__ skip_b,
    float* __restrict__ xl, float* __restrict__ xr, float* __restrict__ xs,
    const int* __restrict__ dst, int* count,
    const int* __restrict__ batch, int* goff,
    int n, int E, int n8, int nbG, int nbH) {
  int bx = blockIdx.x;
  if (bx < nbG) {
    gemm3_body(bx, x, Wl, Wr, Ws, skip_b, xl, xr, xs, n);
  } else if (bx < nbG + nbH) {
    hist_body(bx - nbG, dst, count, E, n8);
  } else {
    goff_body(bx - nbG - nbH, batch, goff, n);
  }
}

// ================= scan chain =============================================
__global__ __launch_bounds__(256) void chunk_sum_kernel(const int* __restrict__ count,
                                                        int* csum, int ntot) {
  int base = blockIdx.x * 1024;
  int tid = threadIdx.x;
  int s = 0;
  for (int q = 0; q < 4; ++q) {
    int i = base + tid * 4 + q;
    if (i < ntot) s += count[i];
  }
  __shared__ int lds[256];
  lds[tid] = s;
  __syncthreads();
  for (int off = 128; off > 0; off >>= 1) {
    if (tid < off) lds[tid] += lds[tid + off];
    __syncthreads();
  }
  if (tid == 0) csum[blockIdx.x] = lds[0];
}

__global__ void small_scan_kernel(int* csum, int nchunks) {
  if (threadIdx.x == 0) {
    int run = 0;
    for (int i = 0; i < nchunks; ++i) { int t = csum[i]; csum[i] = run; run += t; }
  }
}

__global__ __launch_bounds__(256) void scan_apply_kernel(int* count_offs,
                                                         const int* __restrict__ csum,
                                                         int* woff, int ntot) {
  __shared__ int lds[256];
  int base = blockIdx.x * 1024;
  int tid = threadIdx.x;
  int v[4];
  int s = 0;
  for (int q = 0; q < 4; ++q) {
    int i = base + tid * 4 + q;
    v[q] = (i < ntot) ? count_offs[i] : 0;
    s += v[q];
  }
  lds[tid] = s;
  __syncthreads();
  for (int off = 1; off < 256; off <<= 1) {
    int t = (tid >= off) ? lds[tid - off] : 0;
    __syncthreads();
    lds[tid] += t;
    __syncthreads();
  }
  int run = (tid ? lds[tid - 1] : 0) + csum[blockIdx.x];
  for (int q = 0; q < 4; ++q) {
    int i = base + tid * 4 + q;
    if (i < ntot) {
      count_offs[i] = run;
      if (i < ntot - 1) woff[i] = run;  // woff has n entries
      run += v[q];
    }
  }
}

__global__ __launch_bounds__(256) void scatter_kernel(
    const int* __restrict__ src, const int* __restrict__ dst,
    int* woff, int* csr, int E, int n8) {
  int r = blockIdx.x & 7;
  int stripe = blockIdx.x >> 3;
  int lo = r * n8, hi = lo + n8;
  int per = (E + NSTRIPE - 1) / NSTRIPE;
  int s0 = stripe * per;
  int s1 = min(E, s0 + per);
  for (int e = s0 + (int)threadIdx.x; e < s1; e += 256) {
    int d = dst[e];
    if (d >= lo && d < hi) {
      int p = atomicAdd(&woff[d], 1);
      csr[p] = src[e];
    }
  }
}

// ================= K5: GATv2, 2 dst-nodes/wave, float2/lane ===============
// half = lane>>5 selects node, sub = lane&31 owns channels 2*sub, 2*sub+1.
// Elementwise ops pack into v_pk_*_f32; head reduction is 3 shuffle stages
// over 8 lanes. Softmax shifted by self-loop score (one pass, exact alpha).
__global__ __launch_bounds__(256) void edge_kernel(
    const float* __restrict__ xl, const float* __restrict__ xr,
    const int* __restrict__ offs, const int* __restrict__ csr_src,
    const float* __restrict__ att, const float* __restrict__ conv_bias,
    float* __restrict__ out_main, int n) {
  int wave = (blockIdx.x * 256 + threadIdx.x) >> 6;
  int lane = threadIdx.x & 63;
  int half = lane >> 5;
  int sub = lane & 31;
  int node = wave * 2 + half;
  if (wave * 2 >= n) return;           // whole wave out of range
  int nodec = min(node, n - 1);        // clamp; masked at store
  int base = (nodec << 6) | (sub << 1);
  float2 xrc   = *(const float2*)&xr[base];
  float2 xself = *(const float2*)&xl[base];
  float2 att2  = *(const float2*)&att[sub << 1];

  float tx = xself.x + xrc.x, ty = xself.y + xrc.y;
  tx = fmaxf(tx, SLOPE * tx);
  ty = fmaxf(ty, SLOPE * ty);
  float s = tx * att2.x + ty * att2.y;
  s += __shfl_xor(s, 1);
  s += __shfl_xor(s, 2);
  s += __shfl_xor(s, 4);
  const float sself = s;

  int e0 = offs[nodec], e1 = offs[nodec + 1];
  int deg = e1 - e0;
  int iters = max(deg, __shfl_xor(deg, 32));

  float denom = 1.f;
  float a0 = xself.x, a1 = xself.y;
  int i = 0;
  for (; i + 1 < iters; i += 2) {
    bool actA = (i < deg), actB = (i + 1 < deg);
    int ea = actA ? (e0 + i) : e0;
    int eb = actB ? (e0 + i + 1) : e0;
    int ja = csr_src[ea];
    int jb = csr_src[eb];
    float2 va = *(const float2*)&xl[(ja << 6) | (sub << 1)];
    float2 vb = *(const float2*)&xl[(jb << 6) | (sub << 1)];
    float txa = va.x + xrc.x, tya = va.y + xrc.y;
    float txb = vb.x + xrc.x, tyb = vb.y + xrc.y;
    txa = fmaxf(txa, SLOPE * txa); tya = fmaxf(tya, SLOPE * tya);
    txb = fmaxf(txb, SLOPE * txb); tyb = fmaxf(tyb, SLOPE * tyb);
    float sa = txa * att2.x + tya * att2.y;
    float sb = txb * att2.x + tyb * att2.y;
    sa += __shfl_xor(sa, 1);  sb += __shfl_xor(sb, 1);
    sa += __shfl_xor(sa, 2);  sb += __shfl_xor(sb, 2);
    sa += __shfl_xor(sa, 4);  sb += __shfl_xor(sb, 4);
    float pa = actA ? __expf(sa - sself) : 0.f;
    float pb = actB ? __expf(sb - sself) : 0.f;
    denom += pa + pb;
    a0 += pa * va.x + pb * vb.x;
    a1 += pa * va.y + pb * vb.y;
  }
  if (i < iters) {
    bool act = (i < deg);
    int e = act ? (e0 + i) : e0;
    int j = csr_src[e];
    float2 v = *(const float2*)&xl[(j << 6) | (sub << 1)];
    float txa = v.x + xrc.x, tya = v.y + xrc.y;
    txa = fmaxf(txa, SLOPE * txa); tya = fmaxf(tya, SLOPE * tya);
    float sc = txa * att2.x + tya * att2.y;
    sc += __shfl_xor(sc, 1);
    sc += __shfl_xor(sc, 2);
    sc += __shfl_xor(sc, 4);
    float p = act ? __expf(sc - sself) : 0.f;
    denom += p;
    a0 += p * v.x;
    a1 += p * v.y;
  }
  float inv = 1.f / denom;
  float2 bias = *(const float2*)&conv_bias[sub << 1];
  if (node < n)
    *(float2*)&out_main[base] = make_float2(a0 * inv + bias.x, a1 * inv + bias.y);
}

// ================= K6a: per-graph norm partial sums =======================
__global__ __launch_bounds__(256) void stats_part_kernel(
    const float* __restrict__ mainv, const float* __restrict__ xs,
    const int* __restrict__ goff, float* __restrict__ part) {
  int g = blockIdx.x, q = blockIdx.y;
  int start = goff[g], end = goff[g + 1];
  int col = threadIdx.x & 63, grp = threadIdx.x >> 6;
  float s1m = 0.f, s2m = 0.f, s1s = 0.f, s2s = 0.f;
  for (int node = start + q * 4 + grp; node < end; node += 4 * NPART) {
    float vm = mainv[(node << 6) | col];
    float vs = xs[(node << 6) | col];
    s1m += vm; s2m += vm * vm;
    s1s += vs; s2s += vs * vs;
  }
  __shared__ float red[4][4][64];
  red[0][grp][col] = s1m; red[1][grp][col] = s2m;
  red[2][grp][col] = s1s; red[3][grp][col] = s2s;
  __syncthreads();
  if (threadIdx.x < 64) {
    int c = threadIdx.x;
    float* dst = &part[(g * NPART + q) * 256];
#pragma unroll
    for (int st = 0; st < 4; ++st) {
      float s = red[st][0][c] + red[st][1][c] + red[st][2][c] + red[st][3][c];
      dst[st * 64 + c] = s;
    }
  }
}

// ================= K6b: combine partials -> affine A,B ====================
__global__ __launch_bounds__(256) void stats_comb_kernel(
    const float* __restrict__ part, const int* __restrict__ goff,
    const float* __restrict__ bn_w, const float* __restrict__ bn_b,
    const float* __restrict__ bn_ms,
    const float* __restrict__ sn_w, const float* __restrict__ sn_b,
    const float* __restrict__ sn_ms,
    float* __restrict__ Am, float* __restrict__ Bm,
    float* __restrict__ As, float* __restrict__ Bs) {
  int g = blockIdx.x;
  __shared__ float S[4][64];
  int tid = threadIdx.x;
  float s = 0.f;
  for (int q = 0; q < NPART; ++q) s += part[(g * NPART + q) * 256 + tid];
  S[tid >> 6][tid & 63] = s;
  __syncthreads();
  if (tid < 64) {
    int c = tid;
    float S1m = S[0][c], S2m = S[1][c], S1s = S[2][c], S2s = S[3][c];
    float cnt = fmaxf((float)(goff[g + 1] - goff[g]), 1.f);
    float meanM = S1m / cnt;
    float aM = meanM * bn_ms[c];
    float varM = S2m / cnt - 2.f * aM * meanM + aM * aM;
    float invM = rsqrtf(varM + EPSV);
    float am = bn_w[c] * invM;
    Am[g * OUTD + c] = am;
    Bm[g * OUTD + c] = bn_b[c] - am * aM;
    float meanS = S1s / cnt;
    float aS = meanS * sn_ms[c];
    float varS = S2s / cnt - 2.f * aS * meanS + aS * aS;
    float invS = rsqrtf(varS + EPSV);
    float as_ = sn_w[c] * invS;
    As[g * OUTD + c] = as_;
    Bs[g * OUTD + c] = sn_b[c] - as_ * aS;
  }
}

// ================= K7: apply both norms + ELU =============================
__global__ __launch_bounds__(256) void final_kernel(
    const float* __restrict__ xs, const int* __restrict__ batch,
    const float* __restrict__ Am, const float* __restrict__ Bm,
    const float* __restrict__ As, const float* __restrict__ Bs,
    float* out, int n) {
  int wid = (blockIdx.x * blockDim.x + threadIdx.x) >> 6;
  int lane = threadIdx.x & 63;
  if (wid >= n) return;
  int g = batch[wid];
  float mv = out[(wid << 6) | lane];
  float sv = xs[(wid << 6) | lane];
  float v = Am[g * OUTD + lane] * mv + Bm[g * OUTD + lane] +
            As[g * OUTD + lane] * sv + Bs[g * OUTD + lane];
  out[(wid << 6) | lane] = (v > 0.f) ? v : (__expf(v) - 1.f);
}

extern "C" void kernel_launch(void* const* d_in, const int* in_sizes, int n_in,
                              void* d_out, int out_size, void* d_ws, size_t ws_size,
                              hipStream_t stream) {
  const float* x        = (const float*)d_in[0];
  const int*   ei       = (const int*)d_in[1];
  const int*   batch    = (const int*)d_in[2];
  const float* Wl       = (const float*)d_in[3];
  const float* Wr       = (const float*)d_in[4];
  const float* att      = (const float*)d_in[5];
  const float* conv_b   = (const float*)d_in[6];
  const float* skip_W   = (const float*)d_in[7];
  const float* skip_b   = (const float*)d_in[8];
  const float* bn_w     = (const float*)d_in[9];
  const float* bn_b     = (const float*)d_in[10];
  const float* bn_ms    = (const float*)d_in[11];
  const float* sn_w     = (const float*)d_in[12];
  const float* sn_b     = (const float*)d_in[13];
  const float* sn_ms    = (const float*)d_in[14];

  int n = in_sizes[0] / IND;
  int E = in_sizes[1] / 2;
  const int* src = ei;
  const int* dst = ei + E;
  float* out = (float*)d_out;

  // workspace carve-up
  char* w = (char*)d_ws;
  float* xl = (float*)w; w += (size_t)n * OUTD * 4;
  float* xr = (float*)w; w += (size_t)n * OUTD * 4;
  float* xs = (float*)w; w += (size_t)n * OUTD * 4;
  int* count = (int*)w; w += (size_t)(n + 1) * 4;   // becomes offsets in place
  int* woff  = (int*)w; w += (size_t)n * 4;
  int* csr   = (int*)w; w += (size_t)(E + 8) * 4;   // +8: clamped dummy reads
  int* goff  = (int*)w; w += (size_t)(NG + 1) * 4;
  int* csum  = (int*)w; w += 256 * 4;
  float* Am  = (float*)w; w += (size_t)NG * OUTD * 4;
  float* Bm  = (float*)w; w += (size_t)NG * OUTD * 4;
  float* As  = (float*)w; w += (size_t)NG * OUTD * 4;
  float* Bs  = (float*)w; w += (size_t)NG * OUTD * 4;
  float* part = (float*)w; w += (size_t)NG * NPART * 256 * 4;

  int ntot = n + 1;
  int nchunks = (ntot + 1023) / 1024;
  int n8 = (n + 7) / 8;
  int nbG = (n + 63) / 64;
  int nbH = 8 * NSTRIPE;
  int nbB = (n + 255) / 256;

  hipMemsetAsync(count, 0, (size_t)(n + 1) * 4, stream);

  mega1_kernel<<<nbG + nbH + nbB, 256, 0, stream>>>(
      x, Wl, Wr, skip_W, skip_b, xl, xr, xs, dst, count, batch, goff,
      n, E, n8, nbG, nbH);

  chunk_sum_kernel<<<nchunks, 256, 0, stream>>>(count, csum, ntot);
  small_scan_kernel<<<1, 64, 0, stream>>>(csum, nchunks);
  scan_apply_kernel<<<nchunks, 256, 0, stream>>>(count, csum, woff, ntot);
  scatter_kernel<<<8 * NSTRIPE, 256, 0, stream>>>(src, dst, woff, csr, E, n8);

  edge_kernel<<<(n + 7) / 8, 256, 0, stream>>>(xl, xr, count, csr, att, conv_b, out, n);
  dim3 sg(NG, NPART);
  stats_part_kernel<<<sg, 256, 0, stream>>>(out, xs, goff, part);
  stats_comb_kernel<<<NG, 256, 0, stream>>>(part, goff, bn_w, bn_b, bn_ms,
                                            sn_w, sn_b, sn_ms, Am, Bm, As, Bs);
  final_kernel<<<(n + 3) / 4, 256, 0, stream>>>(xs, batch, Am, Bm, As, Bs, out, n);
}